// Round 6
// baseline (65.547 us; speedup 1.0000x reference)
//
#include <hip/hip_runtime.h>
#include <hip/hip_cooperative_groups.h>

namespace cg = cooperative_groups;

// RegionAttention: bin 8M landmarks into a 512x512 grid; out[i] = enhanced[i]
// if any landmark falls in bin i else 1.0f.
//
// Round 6: single cooperative kernel (bin -> dump -> grid.sync -> merge+blend).
// Rounds 4/5 proved pass 1 is neither occupancy- nor MLP-limited; the
// remaining addressable cost is dispatch structure: one launch gap (~2us) and
// the merge kernel's ramp (~1us). Phase C reads the 8MB regions L2-hot.
// Pass-1 body identical to round 5 (controlled: delta attributable to fusion).

#define N_LANDMARKS 8388608
#define N_BINS      262144            // 512*512
#define GRID_COLS   512
#define NWORDS      (N_BINS / 32)     // 8192 dwords = 32 KB bitmask
#define NBLK        256
#define NTHR        1024
#define ITERS       16                // (N_LANDMARKS/2) / (NBLK*NTHR) exactly

// --- fused cooperative kernel -------------------------------------------------

__global__ __launch_bounds__(NTHR)
void fused_kernel(const float4* __restrict__ lm2,
                  const float* __restrict__ ew,
                  float* __restrict__ out,
                  unsigned int* __restrict__ regions) {
    __shared__ unsigned int mask[NWORDS];     // 32 KB
    __shared__ unsigned int part[32][33];     // +1 pad, 4.2 KB
    __shared__ unsigned int merged[32];

    const int tid = threadIdx.x;

    // init mask (vectorized)
    uint4* mask4 = (uint4*)mask;
    #pragma unroll
    for (int w = tid; w < NWORDS / 4; w += NTHR) mask4[w] = make_uint4(0u, 0u, 0u, 0u);
    __syncthreads();

    // phase B: stream landmarks, ds_or into LDS bitmask (round-5 body)
    const int total = NBLK * NTHR;            // 262144 threads
    const int base  = blockIdx.x * NTHR + tid;
    float4 buf[ITERS];
    #pragma unroll
    for (int k = 0; k < ITERS; ++k)
        buf[k] = lm2[base + k * total];

    #pragma unroll
    for (int k = 0; k < ITERS; ++k) {
        float4 v = buf[k];                    // (x0,y0,x1,y1)
        int c0 = min((int)(v.x * 0.0625f), GRID_COLS - 1);
        int r0 = min((int)(v.y * 0.0625f), GRID_COLS - 1);
        int c1 = min((int)(v.z * 0.0625f), GRID_COLS - 1);
        int r1 = min((int)(v.w * 0.0625f), GRID_COLS - 1);
        unsigned int i0 = (unsigned int)(r0 * GRID_COLS + c0);
        unsigned int i1 = (unsigned int)(r1 * GRID_COLS + c1);
        atomicOr(&mask[i0 >> 5], 1u << (i0 & 31));   // ds_or_b32, no return
        atomicOr(&mask[i1 >> 5], 1u << (i1 & 31));
    }
    __syncthreads();

    // dump LDS mask -> per-block region (coalesced dwordx4)
    uint4* dst4 = (uint4*)(regions + (size_t)blockIdx.x * NWORDS);
    #pragma unroll
    for (int w = tid; w < NWORDS / 4; w += NTHR) dst4[w] = mask4[w];

    cg::this_grid().sync();

    // phase C: merge 256 regions for this block's 32 words, then blend.
    // 32 segments x 32 lanes; each lane ORs 8 regions (L2-hot, independent).
    const int wl  = tid & 31;
    const int seg = tid >> 5;                 // 0..31
    const int w   = blockIdx.x * 32 + wl;     // global word index
    const unsigned int* p = regions + (size_t)seg * 8 * NWORDS + w;
    unsigned int m = 0u;
    #pragma unroll
    for (int j = 0; j < 8; ++j)
        m |= p[(size_t)j * NWORDS];
    part[seg][wl] = m;
    __syncthreads();

    if (tid < 32) {
        unsigned int mm = part[0][tid];
        #pragma unroll
        for (int s = 1; s < 32; ++s) mm |= part[s][tid];
        merged[tid] = mm;
    }
    __syncthreads();

    // blend: 1024 threads, one bin each (coalesced 4 KB/block)
    const int g = blockIdx.x * NTHR + tid;    // bin index
    const unsigned int mw = merged[tid >> 5];
    out[g] = ((mw >> (tid & 31)) & 1u) ? ew[g] : 1.0f;
}

// --- fallback: 2-kernel path (round-5 structure) ------------------------------

__global__ __launch_bounds__(NTHR)
void bin_lds_kernel(const float4* __restrict__ lm2,
                    unsigned int* __restrict__ regions) {
    __shared__ unsigned int mask[NWORDS];
    const int tid = threadIdx.x;

    #pragma unroll
    for (int w = tid; w < NWORDS; w += NTHR) mask[w] = 0u;
    __syncthreads();

    const int total = NBLK * NTHR;
    const int base  = blockIdx.x * NTHR + tid;
    float4 buf[ITERS];
    #pragma unroll
    for (int k = 0; k < ITERS; ++k)
        buf[k] = lm2[base + k * total];

    #pragma unroll
    for (int k = 0; k < ITERS; ++k) {
        float4 v = buf[k];
        int c0 = min((int)(v.x * 0.0625f), GRID_COLS - 1);
        int r0 = min((int)(v.y * 0.0625f), GRID_COLS - 1);
        int c1 = min((int)(v.z * 0.0625f), GRID_COLS - 1);
        int r1 = min((int)(v.w * 0.0625f), GRID_COLS - 1);
        unsigned int i0 = (unsigned int)(r0 * GRID_COLS + c0);
        unsigned int i1 = (unsigned int)(r1 * GRID_COLS + c1);
        atomicOr(&mask[i0 >> 5], 1u << (i0 & 31));
        atomicOr(&mask[i1 >> 5], 1u << (i1 & 31));
    }
    __syncthreads();

    unsigned int* dst = regions + (size_t)blockIdx.x * NWORDS;
    #pragma unroll
    for (int w = tid; w < NWORDS; w += NTHR) dst[w] = mask[w];
}

__global__ __launch_bounds__(256)
void merge_blend_kernel(const unsigned int* __restrict__ regions,
                        const float4* __restrict__ ew4,
                        float4* __restrict__ out4) {
    __shared__ unsigned int part[8][33];
    __shared__ unsigned int merged[32];

    const int t   = threadIdx.x;
    const int wl  = t & 31;
    const int seg = t >> 5;
    const int w   = blockIdx.x * 32 + wl;

    const unsigned int* p = regions + (size_t)seg * 32 * NWORDS + w;
    unsigned int m = 0u;
    #pragma unroll
    for (int b = 0; b < 32; ++b)
        m |= p[(size_t)b * NWORDS];
    part[seg][wl] = m;
    __syncthreads();

    if (t < 32) {
        unsigned int mm = part[0][t];
        #pragma unroll
        for (int s = 1; s < 8; ++s) mm |= part[s][t];
        merged[t] = mm;
    }
    __syncthreads();

    const int g4 = blockIdx.x * 256 + t;
    const unsigned int mw = merged[t >> 3];
    const int sh = (t & 7) * 4;
    float4 e = ew4[g4];
    float4 r;
    r.x = ((mw >> (sh + 0)) & 1u) ? e.x : 1.0f;
    r.y = ((mw >> (sh + 1)) & 1u) ? e.y : 1.0f;
    r.z = ((mw >> (sh + 2)) & 1u) ? e.z : 1.0f;
    r.w = ((mw >> (sh + 3)) & 1u) ? e.w : 1.0f;
    out4[g4] = r;
}

extern "C" void kernel_launch(void* const* d_in, const int* in_sizes, int n_in,
                              void* d_out, int out_size, void* d_ws, size_t ws_size,
                              hipStream_t stream) {
    const float4* lm2 = (const float4*)d_in[0];
    const float*  ew  = (const float*)d_in[1];
    float* out        = (float*)d_out;

    const size_t regions_bytes = (size_t)NBLK * NWORDS * sizeof(unsigned int); // 8 MB

    if (ws_size >= regions_bytes) {
        unsigned int* regions = (unsigned int*)d_ws;
        void* args[] = { (void*)&lm2, (void*)&ew, (void*)&out, (void*)&regions };
        hipError_t err = hipLaunchCooperativeKernel((const void*)fused_kernel,
                                                    dim3(NBLK), dim3(NTHR),
                                                    args, 0, stream);
        if (err != hipSuccess) {
            // fallback: classic 2-kernel path
            bin_lds_kernel<<<NBLK, NTHR, 0, stream>>>(lm2, regions);
            merge_blend_kernel<<<NWORDS / 32, 256, 0, stream>>>(
                regions, (const float4*)ew, (float4*)out);
        }
    } else {
        unsigned char* flags = (unsigned char*)d_ws;
        hipMemsetAsync(flags, 0, N_BINS, stream);
        // minimal fallback path for tiny ws (not expected)
        bin_lds_kernel<<<NBLK, NTHR, 0, stream>>>(lm2, (unsigned int*)d_out); // unreachable in practice
        merge_blend_kernel<<<NWORDS / 32, 256, 0, stream>>>(
            (const unsigned int*)d_out, (const float4*)ew, (float4*)out);
    }
}

// Round 7
// 20.376 us; speedup vs baseline: 3.2169x; 3.2169x over previous
//
#include <hip/hip_runtime.h>

// RegionAttention: bin 8M landmarks into a 512x512 grid; out[i] = enhanced[i]
// if any landmark falls in bin i else 1.0f.
//
// Round 7: revert round-6 cooperative fusion (48us/dispatch: grid.sync forced
// device-scope L2 flush + VGPR demotion, VGPR_Count=16). Back to the proven
// round-5 two-kernel structure with two surgical changes:
//  - merge: uint4 region loads, 128 blocks x 256 thr, 16 segs x 16 regions,
//    8 MB fully in flight (pred 2.2 -> ~1.3us).
//  - bin: uint4 LDS init + uint4 dump (shorter serial tail after barrier).
// Ledger: occupancy(R4) null, MLP(R5) null, coop-fusion(R6) negative.

#define N_LANDMARKS 8388608
#define N_BINS      262144            // 512*512
#define GRID_COLS   512
#define NWORDS      (N_BINS / 32)     // 8192 dwords = 32 KB bitmask
#define NQUADS      (NWORDS / 4)      // 2048 uint4 per region
#define P1_BLOCKS   256
#define P1_THREADS  1024
#define P1_ITERS    16                // (N_LANDMARKS/2) / (P1_BLOCKS*P1_THREADS)

// --- pass 1: bin into per-block LDS bitmask, dump coalesced ------------------

__global__ __launch_bounds__(P1_THREADS)
void bin_lds_kernel(const float4* __restrict__ lm2,
                    unsigned int* __restrict__ regions) {
    __shared__ unsigned int mask[NWORDS];
    const int tid = threadIdx.x;

    uint4* mask4 = (uint4*)mask;
    #pragma unroll
    for (int w = tid; w < NQUADS; w += P1_THREADS)
        mask4[w] = make_uint4(0u, 0u, 0u, 0u);
    __syncthreads();

    const int total = P1_BLOCKS * P1_THREADS;          // 262144 threads
    const int base  = blockIdx.x * P1_THREADS + tid;

    float4 buf[P1_ITERS];
    #pragma unroll
    for (int k = 0; k < P1_ITERS; ++k)
        buf[k] = lm2[base + k * total];

    #pragma unroll
    for (int k = 0; k < P1_ITERS; ++k) {
        float4 v = buf[k];                             // (x0,y0,x1,y1)
        int c0 = min((int)(v.x * 0.0625f), GRID_COLS - 1);
        int r0 = min((int)(v.y * 0.0625f), GRID_COLS - 1);
        int c1 = min((int)(v.z * 0.0625f), GRID_COLS - 1);
        int r1 = min((int)(v.w * 0.0625f), GRID_COLS - 1);
        unsigned int i0 = (unsigned int)(r0 * GRID_COLS + c0);
        unsigned int i1 = (unsigned int)(r1 * GRID_COLS + c1);
        atomicOr(&mask[i0 >> 5], 1u << (i0 & 31));     // ds_or_b32, no return
        atomicOr(&mask[i1 >> 5], 1u << (i1 & 31));
    }
    __syncthreads();

    uint4* dst4 = (uint4*)(regions + (size_t)blockIdx.x * NWORDS);
    #pragma unroll
    for (int w = tid; w < NQUADS; w += P1_THREADS)
        dst4[w] = mask4[w];
}

// --- pass 2: OR 256 regions, blend -------------------------------------------
// 128 blocks x 256 thr. Block owns 16 uint4 quads = 64 words = 2048 bins.
// Thread (tq = t&15, seg = t>>4): ORs regions seg*16..seg*16+15 for quad tq.
// Lanes 0-15 read 256 B contiguous per region; 16 independent loads/thread.

__global__ __launch_bounds__(256)
void merge_blend_kernel(const uint4* __restrict__ regions4,
                        const float4* __restrict__ ew4,
                        float4* __restrict__ out4) {
    __shared__ uint4 part[16][17];                     // [seg][quad], +1 pad
    __shared__ uint4 merged[16];

    const int t   = threadIdx.x;
    const int tq  = t & 15;                            // quad within block
    const int seg = t >> 4;                            // 0..15
    const int qbase = blockIdx.x * 16;                 // global quad base

    const uint4* p = regions4 + (size_t)(seg * 16) * NQUADS + qbase + tq;
    uint4 m = make_uint4(0u, 0u, 0u, 0u);
    #pragma unroll
    for (int j = 0; j < 16; ++j) {
        uint4 v = p[(size_t)j * NQUADS];
        m.x |= v.x; m.y |= v.y; m.z |= v.z; m.w |= v.w;
    }
    part[seg][tq] = m;
    __syncthreads();

    if (t < 16) {
        uint4 mm = part[0][t];
        #pragma unroll
        for (int s = 1; s < 16; ++s) {
            uint4 v = part[s][t];
            mm.x |= v.x; mm.y |= v.y; mm.z |= v.z; mm.w |= v.w;
        }
        merged[t] = mm;
    }
    __syncthreads();

    // blend: 64 words = 2048 bins = 512 float4 per block; 2 per thread.
    const unsigned int* mw = (const unsigned int*)merged;
    #pragma unroll
    for (int h = 0; h < 2; ++h) {
        const int lf = h * 256 + t;                    // local float4 0..511
        const int g4 = blockIdx.x * 512 + lf;
        const unsigned int word = mw[lf >> 3];         // same addr per 8 lanes: broadcast
        const int sh = (lf & 7) * 4;
        float4 e = ew4[g4];
        float4 r;
        r.x = ((word >> (sh + 0)) & 1u) ? e.x : 1.0f;
        r.y = ((word >> (sh + 1)) & 1u) ? e.y : 1.0f;
        r.z = ((word >> (sh + 2)) & 1u) ? e.z : 1.0f;
        r.w = ((word >> (sh + 3)) & 1u) ? e.w : 1.0f;
        out4[g4] = r;
    }
}

// --- fallback (small ws): byte-flag path --------------------------------------

__global__ void scatter_flags_kernel(const float4* __restrict__ lm2,
                                     unsigned char* __restrict__ flags, int n4) {
    int i = blockIdx.x * blockDim.x + threadIdx.x;
    const int stride = gridDim.x * blockDim.x;
    for (; i < n4; i += stride) {
        float4 v = lm2[i];
        int c0 = min((int)(v.x * 0.0625f), GRID_COLS - 1);
        int r0 = min((int)(v.y * 0.0625f), GRID_COLS - 1);
        int c1 = min((int)(v.z * 0.0625f), GRID_COLS - 1);
        int r1 = min((int)(v.w * 0.0625f), GRID_COLS - 1);
        flags[r0 * GRID_COLS + c0] = (unsigned char)1;
        flags[r1 * GRID_COLS + c1] = (unsigned char)1;
    }
}

__global__ void blend_kernel(const unsigned char* __restrict__ flags,
                             const float* __restrict__ ew,
                             float* __restrict__ out) {
    int i = blockIdx.x * blockDim.x + threadIdx.x;
    out[i] = flags[i] ? ew[i] : 1.0f;
}

extern "C" void kernel_launch(void* const* d_in, const int* in_sizes, int n_in,
                              void* d_out, int out_size, void* d_ws, size_t ws_size,
                              hipStream_t stream) {
    const float4* lm2 = (const float4*)d_in[0];
    const float*  ew  = (const float*)d_in[1];
    float* out        = (float*)d_out;

    const size_t regions_bytes = (size_t)P1_BLOCKS * NWORDS * sizeof(unsigned int); // 8 MB

    if (ws_size >= regions_bytes) {
        unsigned int* regions = (unsigned int*)d_ws;
        bin_lds_kernel<<<P1_BLOCKS, P1_THREADS, 0, stream>>>(lm2, regions);
        merge_blend_kernel<<<NQUADS / 16, 256, 0, stream>>>(
            (const uint4*)regions, (const float4*)ew, (float4*)out);
    } else {
        unsigned char* flags = (unsigned char*)d_ws;
        hipMemsetAsync(flags, 0, N_BINS, stream);
        scatter_flags_kernel<<<2048, 256, 0, stream>>>(lm2, flags, N_LANDMARKS / 2);
        blend_kernel<<<N_BINS / 256, 256, 0, stream>>>(flags, ew, out);
    }
}